// Round 2
// baseline (5441.100 us; speedup 1.0000x reference)
//
#include <hip/hip_runtime.h>
#include <cstddef>
#include <cstdint>

// Problem constants (B=2, L=4096, D=2048, H=16, head dim 128)
#define BATCH 2
#define SEQL  4096
#define DIM   2048
#define HEADS 16
#define HK    128          // head dim for q/k/g and v
#define MROWS (BATCH * SEQL)          // 8192 GEMM rows
#define NELEM ((size_t)MROWS * DIM)   // 16,777,216 per activation buffer

// ---------------------------------------------------------------------------
// GEMM: C[m,n] = sum_d A[m,d] * W[n,d]   (i.e. A @ W^T, both row-major)
// mode: 0 = plain, 1 = scale by K^-0.5 (q), 2 = sigmoid (eg = exp(logsigmoid))
// 128x128 block tile, 256 threads, 8x8 per thread, BK=16, 1-deep prefetch.
// fp32 vector-ALU (no fp32 MFMA on CDNA4); ~roofline for this dtype.
// ---------------------------------------------------------------------------
__global__ __launch_bounds__(256)
void gemm_nt(const float* __restrict__ A, const float* __restrict__ W,
             float* __restrict__ C, int mode) {
  constexpr int BM = 128, BN = 128, BK = 16;
  // As: transposed [k][row], +4 pad. Bs: 16 groups of 8 cols padded to 12
  // floats so per-thread b128 reads land 2-way on banks (free).
  __shared__ __align__(16) float As[BK][BM + 4];
  __shared__ __align__(16) float Bs[BK][16 * 12];

  const int tid  = threadIdx.x;
  const int bm   = blockIdx.y * BM;
  const int bn   = blockIdx.x * BN;
  const int tm   = (tid >> 4) * 8;   // output row offset within tile
  const int bg   = tid & 15;         // output column group (8 cols)
  const int srow = tid >> 2;         // staging row 0..63 (and +64)
  const int sc4  = (tid & 3) * 4;    // staging k-offset 0,4,8,12
  const int g0 = srow >> 3, w0 = srow & 7;
  const int g1 = g0 + 8;             // (srow+64)>>3

  const float* Ap = A + (size_t)(bm + srow) * DIM + sc4;
  const float* Bp = W + (size_t)(bn + srow) * DIM + sc4;

  float4 a0 = *(const float4*)(Ap);
  float4 a1 = *(const float4*)(Ap + (size_t)64 * DIM);
  float4 b0 = *(const float4*)(Bp);
  float4 b1 = *(const float4*)(Bp + (size_t)64 * DIM);

  float acc[8][8];
#pragma unroll
  for (int i = 0; i < 8; ++i)
#pragma unroll
    for (int j = 0; j < 8; ++j) acc[i][j] = 0.f;

  for (int k0 = 0; k0 < DIM; k0 += BK) {
    As[sc4 + 0][srow] = a0.x;  As[sc4 + 1][srow] = a0.y;
    As[sc4 + 2][srow] = a0.z;  As[sc4 + 3][srow] = a0.w;
    As[sc4 + 0][srow + 64] = a1.x;  As[sc4 + 1][srow + 64] = a1.y;
    As[sc4 + 2][srow + 64] = a1.z;  As[sc4 + 3][srow + 64] = a1.w;
    Bs[sc4 + 0][g0 * 12 + w0] = b0.x;  Bs[sc4 + 1][g0 * 12 + w0] = b0.y;
    Bs[sc4 + 2][g0 * 12 + w0] = b0.z;  Bs[sc4 + 3][g0 * 12 + w0] = b0.w;
    Bs[sc4 + 0][g1 * 12 + w0] = b1.x;  Bs[sc4 + 1][g1 * 12 + w0] = b1.y;
    Bs[sc4 + 2][g1 * 12 + w0] = b1.z;  Bs[sc4 + 3][g1 * 12 + w0] = b1.w;
    __syncthreads();
    if (k0 + BK < DIM) {  // prefetch next tile (overlaps with compute below)
      a0 = *(const float4*)(Ap + k0 + BK);
      a1 = *(const float4*)(Ap + (size_t)64 * DIM + k0 + BK);
      b0 = *(const float4*)(Bp + k0 + BK);
      b1 = *(const float4*)(Bp + (size_t)64 * DIM + k0 + BK);
    }
#pragma unroll
    for (int d = 0; d < BK; ++d) {
      float av[8], bv[8];
      *(float4*)&av[0] = *(const float4*)&As[d][tm];
      *(float4*)&av[4] = *(const float4*)&As[d][tm + 4];
      *(float4*)&bv[0] = *(const float4*)&Bs[d][bg * 12];
      *(float4*)&bv[4] = *(const float4*)&Bs[d][bg * 12 + 4];
#pragma unroll
      for (int i = 0; i < 8; ++i)
#pragma unroll
        for (int j = 0; j < 8; ++j)
          acc[i][j] = fmaf(av[i], bv[j], acc[i][j]);
    }
    __syncthreads();
  }

  const float qscale = 0.08838834764831845f;  // 128^-0.5
#pragma unroll
  for (int i = 0; i < 8; ++i) {
    float vout[8];
#pragma unroll
    for (int j = 0; j < 8; ++j) {
      float z = acc[i][j];
      if (mode == 1) z *= qscale;
      else if (mode == 2) z = 1.0f / (1.0f + expf(-z));  // sigmoid == exp(logsigmoid)
      vout[j] = z;
    }
    float* cp = C + (size_t)(bm + tm + i) * DIM + bn + bg * 8;
    *(float4*)cp       = *(const float4*)&vout[0];
    *(float4*)(cp + 4) = *(const float4*)&vout[4];
  }
}

// ---------------------------------------------------------------------------
// GLA recurrence, chunked. Grid = B*H*NVT blocks (v-tile = 16 cols), 256 thr.
// Wave w owns 4 columns: col = w*4 + (lane>>4); lane&15 = row-group r
// (8 state rows r*8..r*8+7 in VGPRs). y-reduce = 4-step shfl_xor butterfly
// over lane bits 0..3 (wave-local, no barrier). Time chunked TC=8: one
// barrier per chunk, q/k/e/v double-buffered in LDS, next chunk prefetched
// into registers at chunk top. q/k/e LDS rows XOR-swizzled (f ^ (f>>3) on
// float4 groups, bijective) -> 16-lane stride-32B b128 reads go 4-way -> 2-way
// (free per m136).
// ---------------------------------------------------------------------------
#define VT  16
#define NVT (HK / VT)  // 8
#define TC  8
#define NCHUNK (SEQL / TC)  // 512

__global__ __launch_bounds__(256)
void gla_rec(const float* __restrict__ q, const float* __restrict__ k,
             const float* __restrict__ v, const float* __restrict__ eg,
             float* __restrict__ y, float* __restrict__ stout) {
  const int bid = blockIdx.x;          // (bh * NVT + vt)
  const int vt  = bid & (NVT - 1);
  const int bh  = bid >> 3;            // b*H + h
  const int b   = bh >> 4;
  const int h   = bh & (HEADS - 1);

  const int tid = threadIdx.x;
  const int w   = tid >> 6;            // wave 0..3
  const int l   = tid & 63;
  const int col = w * 4 + (l >> 4);    // 0..15 within block
  const int r   = l & 15;              // rows r*8 .. r*8+7

  __shared__ __align__(16) float qs[2][TC][HK];
  __shared__ __align__(16) float ks[2][TC][HK];
  __shared__ __align__(16) float es[2][TC][HK];
  __shared__ __align__(16) float vs[2][TC][VT];

  const size_t base = (size_t)b * SEQL * DIM + (size_t)h * HK;

  // staging map: thread loads float4-group f=tid&31 of step st_t=tid>>5 for
  // each of q/k/e; threads 0..31 additionally load v.
  const int st_t  = tid >> 5;
  const int st_f  = tid & 31;
  const int st_sf = st_f ^ (st_f >> 3);      // swizzled store slot
  const bool vload = (tid < 32);
  const int vt_t  = tid >> 2;
  const int vt_f  = tid & 3;

  const float* qp = q  + base + (size_t)st_t * DIM + st_f * 4;
  const float* kp = k  + base + (size_t)st_t * DIM + st_f * 4;
  const float* ep = eg + base + (size_t)st_t * DIM + st_f * 4;
  const float* vp = v  + base + (size_t)vt_t * DIM + vt * VT + vt_f * 4;

  // swizzled read byte-offsets for this thread's two row-groups (constant)
  const int g0 = (2 * r) ^ (r >> 2);
  const int g1 = (2 * r + 1) ^ (r >> 2);
  const int o0 = g0 * 16;
  const int o1 = g1 * 16;

  float S[8];
#pragma unroll
  for (int i = 0; i < 8; ++i) S[i] = 0.f;

  // chunk 0 -> LDS buffer 0
  {
    float4 rq = *(const float4*)qp;
    float4 rk = *(const float4*)kp;
    float4 re = *(const float4*)ep;
    *(float4*)((char*)&qs[0][st_t][0] + st_sf * 16) = rq;
    *(float4*)((char*)&ks[0][st_t][0] + st_sf * 16) = rk;
    *(float4*)((char*)&es[0][st_t][0] + st_sf * 16) = re;
    if (vload) *(float4*)&vs[0][vt_t][vt_f * 4] = *(const float4*)vp;
  }
  __syncthreads();

  const size_t ycol = base + (size_t)vt * VT + col;
  int p = 0;
  for (int c = 0; c < NCHUNK; ++c) {
    // prefetch chunk c+1 into registers (latency hides under compute)
    float4 rq, rk, re, rv;
    const bool pf = (c + 1 < NCHUNK);
    if (pf) {
      const size_t off = (size_t)(c + 1) * TC * DIM;
      rq = *(const float4*)(qp + off);
      rk = *(const float4*)(kp + off);
      re = *(const float4*)(ep + off);
      if (vload) rv = *(const float4*)(vp + off);
    }

#pragma unroll
    for (int t = 0; t < TC; ++t) {
      const float vvt = vs[p][t][col];
      const char* qb = (const char*)&qs[p][t][0];
      const char* kb = (const char*)&ks[p][t][0];
      const char* eb = (const char*)&es[p][t][0];
      const float4 q0 = *(const float4*)(qb + o0);
      const float4 q1 = *(const float4*)(qb + o1);
      const float4 k0 = *(const float4*)(kb + o0);
      const float4 k1 = *(const float4*)(kb + o1);
      const float4 e0 = *(const float4*)(eb + o0);
      const float4 e1 = *(const float4*)(eb + o1);
      float psum;
      S[0] = fmaf(S[0], e0.x, k0.x * vvt); psum = q0.x * S[0];
      S[1] = fmaf(S[1], e0.y, k0.y * vvt); psum = fmaf(q0.y, S[1], psum);
      S[2] = fmaf(S[2], e0.z, k0.z * vvt); psum = fmaf(q0.z, S[2], psum);
      S[3] = fmaf(S[3], e0.w, k0.w * vvt); psum = fmaf(q0.w, S[3], psum);
      S[4] = fmaf(S[4], e1.x, k1.x * vvt); psum = fmaf(q1.x, S[4], psum);
      S[5] = fmaf(S[5], e1.y, k1.y * vvt); psum = fmaf(q1.y, S[5], psum);
      S[6] = fmaf(S[6], e1.z, k1.z * vvt); psum = fmaf(q1.z, S[6], psum);
      S[7] = fmaf(S[7], e1.w, k1.w * vvt); psum = fmaf(q1.w, S[7], psum);
      // wave-local reduce over the 16 row-groups (lane bits 0..3)
      psum += __shfl_xor(psum, 1);
      psum += __shfl_xor(psum, 2);
      psum += __shfl_xor(psum, 4);
      psum += __shfl_xor(psum, 8);
      if (r == 0) y[ycol + (size_t)(c * TC + t) * DIM] = psum;
    }

    if (pf) {  // write prefetched chunk into the other buffer (no race: p^1)
      *(float4*)((char*)&qs[p ^ 1][st_t][0] + st_sf * 16) = rq;
      *(float4*)((char*)&ks[p ^ 1][st_t][0] + st_sf * 16) = rk;
      *(float4*)((char*)&es[p ^ 1][st_t][0] + st_sf * 16) = re;
      if (vload) *(float4*)&vs[p ^ 1][vt_t][vt_f * 4] = rv;
      __syncthreads();
      p ^= 1;
    }
  }

#pragma unroll
  for (int i = 0; i < 8; ++i) {
    const int row = r * 8 + i;
    stout[((size_t)bh * HK + row) * HK + vt * VT + col] = S[i];
  }
}

// ---------------------------------------------------------------------------
// Row LayerNorm over D=2048. One block per row, 256 threads x 8 elements.
// ---------------------------------------------------------------------------
__global__ __launch_bounds__(256)
void ln_rows(const float* __restrict__ src, float* __restrict__ dst,
             const float* __restrict__ gamma, const float* __restrict__ beta) {
  const int row = blockIdx.x;
  const int tid = threadIdx.x;
  const float* sr = src + (size_t)row * DIM;
  float vals[8];
  *(float4*)&vals[0] = *(const float4*)&sr[tid * 8];
  *(float4*)&vals[4] = *(const float4*)&sr[tid * 8 + 4];

  float s = 0.f;
#pragma unroll
  for (int i = 0; i < 8; ++i) s += vals[i];
#pragma unroll
  for (int off = 32; off >= 1; off >>= 1) s += __shfl_xor(s, off);

  __shared__ float red[2][4];
  const int wv = tid >> 6, lane = tid & 63;
  if (lane == 0) red[0][wv] = s;
  __syncthreads();
  const float mu = (red[0][0] + red[0][1] + red[0][2] + red[0][3]) * (1.f / DIM);

  float sq = 0.f;
#pragma unroll
  for (int i = 0; i < 8; ++i) { const float d = vals[i] - mu; sq += d * d; }
#pragma unroll
  for (int off = 32; off >= 1; off >>= 1) sq += __shfl_xor(sq, off);
  if (lane == 0) red[1][wv] = sq;
  __syncthreads();
  const float var  = (red[1][0] + red[1][1] + red[1][2] + red[1][3]) * (1.f / DIM);
  const float rstd = 1.0f / sqrtf(var + 1e-5f);

  float gg[8], bb[8];
  *(float4*)&gg[0] = *(const float4*)&gamma[tid * 8];
  *(float4*)&gg[4] = *(const float4*)&gamma[tid * 8 + 4];
  *(float4*)&bb[0] = *(const float4*)&beta[tid * 8];
  *(float4*)&bb[4] = *(const float4*)&beta[tid * 8 + 4];

  float out[8];
#pragma unroll
  for (int i = 0; i < 8; ++i)
    out[i] = (vals[i] - mu) * rstd * gg[i] + bb[i];
  float* dr = dst + (size_t)row * DIM;
  *(float4*)&dr[tid * 8]     = *(const float4*)&out[0];
  *(float4*)&dr[tid * 8 + 4] = *(const float4*)&out[4];
}

// ---------------------------------------------------------------------------
extern "C" void kernel_launch(void* const* d_in, const int* in_sizes, int n_in,
                              void* d_out, int out_size, void* d_ws, size_t ws_size,
                              hipStream_t stream) {
  const float* x     = (const float*)d_in[0];
  const float* Wq    = (const float*)d_in[1];
  const float* Wk    = (const float*)d_in[2];
  const float* Wv    = (const float*)d_in[3];
  const float* Wg    = (const float*)d_in[4];
  const float* Wo    = (const float*)d_in[5];
  const float* gamma = (const float*)d_in[6];
  const float* beta  = (const float*)d_in[7];

  float* out   = (float*)d_out;                 // o: [B,L,D]
  float* state = out + NELEM;                   // final_state: [B,H,K,V]

  // workspace: 4 fp32 activation buffers (256 MB total)
  float* wsq = (float*)d_ws;
  float* wsk = wsq + NELEM;
  float* wsv = wsk + NELEM;
  float* wse = wsv + NELEM;
  // y lives temporarily in the d_out o-region; LN writes into wsq (free by then)

  dim3 gemm_grid(DIM / 128, MROWS / 128);       // (16, 64)
  gemm_nt<<<gemm_grid, 256, 0, stream>>>(x, Wq, wsq, 1);
  gemm_nt<<<gemm_grid, 256, 0, stream>>>(x, Wk, wsk, 0);
  gemm_nt<<<gemm_grid, 256, 0, stream>>>(x, Wv, wsv, 0);
  gemm_nt<<<gemm_grid, 256, 0, stream>>>(x, Wg, wse, 2);

  gla_rec<<<BATCH * HEADS * NVT, 256, 0, stream>>>(wsq, wsk, wsv, wse, out, state);

  ln_rows<<<MROWS, 256, 0, stream>>>(out, wsq, gamma, beta);

  gemm_nt<<<gemm_grid, 256, 0, stream>>>(wsq, Wo, out, 0);
}